// Round 10
// baseline (1387.675 us; speedup 1.0000x reference)
//
#include <hip/hip_runtime.h>
#include <hip/hip_bf16.h>

typedef unsigned short u16;
typedef unsigned int u32;
typedef __attribute__((ext_vector_type(4))) float f32x4;
typedef __attribute__((ext_vector_type(8))) short bf16x8;

#define DEVI static __device__ __forceinline__

DEVI u16 f2bf(float f) {
  u32 u = __builtin_bit_cast(u32, f);
  u += 0x7fffu + ((u >> 16) & 1u);
  return (u16)(u >> 16);
}

DEVI void gload_lds16(const void* g, void* l) {
  __builtin_amdgcn_global_load_lds(
      (const __attribute__((address_space(1))) u32*)g,
      (__attribute__((address_space(3))) u32*)l, 16, 0, 0);
}

template<int N> DEVI void wait_vm() {
  if constexpr (N == 0)      asm volatile("s_waitcnt vmcnt(0)" ::: "memory");
  else if constexpr (N == 5) asm volatile("s_waitcnt vmcnt(5)" ::: "memory");
  else if constexpr (N == 6) asm volatile("s_waitcnt vmcnt(6)" ::: "memory");
  else if constexpr (N == 8) asm volatile("s_waitcnt vmcnt(8)" ::: "memory");
  else                       asm volatile("s_waitcnt vmcnt(0)" ::: "memory");
}
DEVI void lgkm_barrier() {
  asm volatile("s_waitcnt lgkmcnt(0)\n\ts_barrier" ::: "memory");
}

struct Aregs { f32x4 v0, v1; uint4 h; };

// ---------------------------------------------------------------------------
// C[BM x BN_T] = A[m0.., k0..k0+klen] @ Bt[n0.., k]^T (bf16 Bt).
// 512 thr = 8 waves (1x8 over BN_T cols). A: reg-staged (fp32->bf16 or bf16),
// 2 named reg sets, XOR-swizzled ds_write into LDS dbuf. B: per-wave slice
// via global_load_lds (inverse-swizzled source), DEPTH<=2 deep, NB=DEPTH+1
// bufs. Counted waits: VMW = DEPTH*(LA+LB) (verified vs the writeA implicit
// drain for DEPTH<=2; DEPTH=3 is UNSOUND with this issue order - prologue
// makes the count a no-op at iter 1). One lgkmcnt(0)+s_barrier per step;
// vmcnt(0) drain before epilogue. NT even at all call sites.
// (BM,BK) in {(64,64),(128,32)}: one 16B A chunk per thread.
// XMAP 0: q=(bid&7)*G8+(bid>>3); sub=q%SPL (nh or kc); m0=(q/SPL)*BM.
// XMAP 1: (P2) xcd-pair owns one (nh,kc) combo -> per-XCD B slice = 4MB = L2.
// EPI 0: bf16 transposed outh[n][M]+m.  EPI 2: fp32 partial outf+kc*M*BN_FULL.
// launch_bounds(512,4): <=128 VGPR -> 2 blocks/CU. Worst acc = 8x2x4 = 64.
// ---------------------------------------------------------------------------
template<int BM, int BN_FULL, int BN_T, int BK, bool AF32, int EPI, int XMAP,
         int NSPL, int KSPL, int DEPTH>
__global__ __launch_bounds__(512, 4)
void gk(const void* __restrict__ Ap, const u16* __restrict__ Bt,
        const int Kfull, const int M, float* __restrict__ outf,
        u16* __restrict__ outh)
{
  constexpr int TN = BN_T / 8;
  constexpr int MF = BM / 16, NF = TN / 16, KK = BK / 32;
  constexpr int ABYTES = BM * BK * 2;      // 8 KiB both configs
  constexpr int SLICE = TN * BK * 2;
  constexpr int LB = SLICE / 1024;
  constexpr int LA = AF32 ? 2 : 1;
  constexpr int NB = DEPTH + 1;
  constexpr int VMW = DEPTH * (LA + LB);
  constexpr int CPR = BK / 8;
  constexpr int SPL = NSPL * KSPL;
  static_assert(BM * BK == 4096, "one 16B A chunk per thread");
  static_assert(DEPTH <= 2, "DEPTH=3 wait algebra unsound (see r9 post-mortem)");

  __shared__ char smem[2 * ABYTES + NB * 8 * SLICE];

  const int tid = threadIdx.x;
  const int w = tid >> 6, l = tid & 63;
  const int l15 = l & 15, l4 = l >> 4;

  int m0, nh, kc;
  if constexpr (XMAP == 1) {
    // grid 512: XCD pair owns one (nh,kc); per-XCD B working set L2-resident
    const int xcd = blockIdx.x & 7;
    const int combo = xcd >> 1;
    nh = combo & 1;
    kc = combo >> 1;
    m0 = ((int)(blockIdx.x >> 3) + (xcd & 1) * 64) * BM;
  } else {
    const int G8 = gridDim.x >> 3;
    const int q = (blockIdx.x & 7) * G8 + (blockIdx.x >> 3);
    const int sub = q % SPL;
    m0 = (q / SPL) * BM;
    nh = (NSPL == 2) ? sub : 0;
    kc = (KSPL == 2) ? sub : 0;
  }
  const int n0 = nh * BN_T;
  const int klen = Kfull / KSPL;
  const int k0 = kc * klen;
  const int NT = klen / BK;

  auto off = [&](int row, int chq) -> int {
    if constexpr (BK == 64) return row * 128 + ((chq ^ (row & 7)) << 4);
    else                    return row * 64 + ((chq ^ ((row >> 1) & 3)) << 4);
  };

  const int ar = tid / CPR, ac = tid % CPR;
  const int apos = off(ar, ac);
  const size_t Abase = (size_t)(m0 + ar) * Kfull + k0 + (size_t)ac * 8;

  char* const bslice = smem + 2 * ABYTES + w * SLICE;

  f32x4 acc[MF][NF];
#pragma unroll
  for (int i = 0; i < MF; ++i)
#pragma unroll
    for (int j = 0; j < NF; ++j) acc[i][j] = (f32x4){0.f, 0.f, 0.f, 0.f};

  Aregs R0, R1;

  auto issueA = [&](Aregs& R, int t) {
    if constexpr (AF32) {
      const float* p = (const float*)Ap + Abase + (size_t)t * BK;
      R.v0 = *(const f32x4*)p;
      R.v1 = *(const f32x4*)(p + 4);
    } else {
      const u16* p = (const u16*)Ap + Abase + (size_t)t * BK;
      R.h = *(const uint4*)p;
    }
  };
  auto writeA = [&](int nb, Aregs& R) {
    uint4 pk;
    if constexpr (AF32) {
      pk.x = (u32)f2bf(R.v0[0]) | ((u32)f2bf(R.v0[1]) << 16);
      pk.y = (u32)f2bf(R.v0[2]) | ((u32)f2bf(R.v0[3]) << 16);
      pk.z = (u32)f2bf(R.v1[0]) | ((u32)f2bf(R.v1[1]) << 16);
      pk.w = (u32)f2bf(R.v1[2]) | ((u32)f2bf(R.v1[3]) << 16);
    } else {
      pk = R.h;
    }
    *(uint4*)(smem + nb * ABYTES + apos) = pk;
  };
  auto issueB = [&](int nb, int t) {
    const char* bsrc = (const char*)Bt +
                       ((size_t)(n0 + w * TN) * Kfull + k0 +
                        (size_t)t * BK) * 2;
    char* bd = bslice + nb * (8 * SLICE);
#pragma unroll
    for (int i = 0; i < LB; ++i) {
      const int p = i * 1024 + l * 16;
      const int nl = (BK == 64) ? (p >> 7) : (p >> 6);
      const int chp = (p & (BK * 2 - 1)) >> 4;
      const int chq = (BK == 64) ? (chp ^ (nl & 7)) : (chp ^ ((nl >> 1) & 3));
      gload_lds16(bsrc + (size_t)nl * ((size_t)Kfull * 2) + chq * 16,
                  bd + i * 1024);
    }
  };
  auto compute = [&](int ab, int bb) {
    const char* A = smem + ab * ABYTES;
    const char* Bs = bslice + bb * (8 * SLICE);
#pragma unroll
    for (int kk = 0; kk < KK; ++kk) {
      bf16x8 af[MF];
      uint4 bfr[NF];
#pragma unroll
      for (int mi = 0; mi < MF; ++mi)
        af[mi] = *(const bf16x8*)(A + off(mi * 16 + l15, kk * 4 + l4));
#pragma unroll
      for (int ni = 0; ni < NF; ++ni)
        bfr[ni] = *(const uint4*)(Bs + off(ni * 16 + l15, kk * 4 + l4));
      __builtin_amdgcn_s_setprio(1);
#pragma unroll
      for (int mi = 0; mi < MF; ++mi)
#pragma unroll
        for (int ni = 0; ni < NF; ++ni)
          acc[mi][ni] = __builtin_amdgcn_mfma_f32_16x16x32_bf16(
              af[mi], __builtin_bit_cast(bf16x8, bfr[ni]), acc[mi][ni],
              0, 0, 0);
      __builtin_amdgcn_s_setprio(0);
    }
  };

  // prologue
  issueB(0, 0);
  issueA(R0, 0);
  issueA(R1, NT > 1 ? 1 : 0);
  if constexpr (DEPTH == 2) issueB(1, NT > 1 ? 1 : 0);
  writeA(0, R0);
  lgkm_barrier();

  int bc = 0, bi = DEPTH % NB;
  int t2 = 0;

#define SUBSTEP(RI, RW, ABUF)                                                \
  {                                                                          \
    const int tA = (t2 + 2 < NT) ? t2 + 2 : NT - 1;                          \
    const int tB = (t2 + DEPTH < NT) ? t2 + DEPTH : NT - 1;                  \
    issueA(RI, tA);                                                          \
    issueB(bi, tB);                                                          \
    wait_vm<VMW>();                                                          \
    compute(ABUF, bc);                                                       \
    writeA(ABUF ^ 1, RW);                                                    \
    lgkm_barrier();                                                          \
    bc = (bc + 1 == NB) ? 0 : bc + 1;                                        \
    bi = (bi + 1 == NB) ? 0 : bi + 1;                                        \
    ++t2;                                                                    \
  }

  for (int it = 0; it < NT / 2; ++it) {
    SUBSTEP(R0, R1, 0);
    SUBSTEP(R1, R0, 1);
  }
#undef SUBSTEP

  wait_vm<0>();   // drain clamped-tail gload_lds

  const int mrow0 = m0 + l4 * 4;
#pragma unroll
  for (int ni = 0; ni < NF; ++ni) {
    const int n = n0 + w * TN + ni * 16 + l15;
    if constexpr (EPI == 0) {
#pragma unroll
      for (int mi = 0; mi < MF; ++mi) {
        const int m = mrow0 + mi * 16;
        ushort4 o;
        o.x = f2bf(acc[mi][ni][0]);
        o.y = f2bf(acc[mi][ni][1]);
        o.z = f2bf(acc[mi][ni][2]);
        o.w = f2bf(acc[mi][ni][3]);
        *(ushort4*)(outh + (size_t)n * M + m) = o;
      }
    } else {
      float* Pout = outf + (size_t)kc * ((size_t)M * BN_FULL);
#pragma unroll
      for (int mi = 0; mi < MF; ++mi)
#pragma unroll
        for (int r = 0; r < 4; ++r)
          Pout[(size_t)(mrow0 + mi * 16 + r) * BN_FULL + n] = acc[mi][ni][r];
    }
  }
}

// ---------------------------------------------------------------------------
__global__ __launch_bounds__(256)
void bn1_cast_k(const float* __restrict__ x, const float* __restrict__ g,
                const float* __restrict__ be, const float* __restrict__ rm,
                const float* __restrict__ rv, u16* __restrict__ out)
{
  const size_t i8 = ((size_t)blockIdx.x * 256 + threadIdx.x) * 8;
  const f32x4 v0 = *(const f32x4*)(x + i8);
  const f32x4 v1 = *(const f32x4*)(x + i8 + 4);
  const int f0 = (int)(i8 & 511);
  u16 u[8];
#pragma unroll
  for (int e = 0; e < 8; ++e) {
    const int f = f0 + e;
    const float sc = g[f] * rsqrtf(rv[f] + 1e-5f);
    const float v = (e < 4) ? v0[e] : v1[e - 4];
    u[e] = f2bf((v - rm[f]) * sc + be[f]);
  }
  uint4 o;
  o.x = (u32)u[0] | ((u32)u[1] << 16);
  o.y = (u32)u[2] | ((u32)u[3] << 16);
  o.z = (u32)u[4] | ((u32)u[5] << 16);
  o.w = (u32)u[6] | ((u32)u[7] << 16);
  *(uint4*)(out + i8) = o;
}

__global__ __launch_bounds__(256)
void tcvt_k(const float* __restrict__ in, u16* __restrict__ out, int rowlen)
{
  const int o = blockIdx.x * 256 + threadIdx.x;
  out[o] = f2bf(in[(size_t)(o & 511) * rowlen + (o >> 9)]);
}

// x2 = bn2(relu(P0 + P1 + b1)); row length 512
__global__ __launch_bounds__(256)
void comb_bn_k(const float* __restrict__ P, const float* __restrict__ b1,
               const float* __restrict__ g2, const float* __restrict__ be2,
               const float* __restrict__ rm2, const float* __restrict__ rv2,
               float* __restrict__ out)
{
  const size_t i4 = ((size_t)blockIdx.x * 256 + threadIdx.x) * 4;
  const f32x4 p0 = *(const f32x4*)(P + i4);
  const f32x4 p1 = *(const f32x4*)(P + (size_t)16384 * 512 + i4);
  const int f0 = (int)(i4 & 511);
  f32x4 o;
#pragma unroll
  for (int e = 0; e < 4; ++e) {
    const int f = f0 + e;
    const float s = fmaxf(p0[e] + p1[e] + b1[f], 0.f);
    const float sc = g2[f] * rsqrtf(rv2[f] + 1e-5f);
    o[e] = s * sc + (be2[f] - rm2[f] * sc);
  }
  *(f32x4*)(out + i4) = o;
}

// x1 = P0 + P1 + b2; row length 128
__global__ __launch_bounds__(256)
void comb_k(const float* __restrict__ P, const float* __restrict__ b2,
            float* __restrict__ out)
{
  const size_t i4 = ((size_t)blockIdx.x * 256 + threadIdx.x) * 4;
  const f32x4 p0 = *(const f32x4*)(P + i4);
  const f32x4 p1 = *(const f32x4*)(P + (size_t)16384 * 128 + i4);
  const int f0 = (int)(i4 & 127);
  f32x4 o;
#pragma unroll
  for (int e = 0; e < 4; ++e) o[e] = p0[e] + p1[e] + b2[f0 + e];
  *(f32x4*)(out + i4) = o;
}

// ---------------------------------------------------------------------------
extern "C" void kernel_launch(void* const* d_in, const int* in_sizes, int n_in,
                              void* d_out, int out_size, void* d_ws, size_t ws_size,
                              hipStream_t stream)
{
  const float* x   = (const float*)d_in[0];
  const float* a   = (const float*)d_in[1];
  const float* w1  = (const float*)d_in[2];
  const float* b1  = (const float*)d_in[3];
  const float* w2  = (const float*)d_in[4];
  const float* b2  = (const float*)d_in[5];
  const float* g1  = (const float*)d_in[6];
  const float* be1 = (const float*)d_in[7];
  const float* rm1 = (const float*)d_in[8];
  const float* rv1 = (const float*)d_in[9];
  const float* g2  = (const float*)d_in[10];
  const float* be2 = (const float*)d_in[11];
  const float* rm2 = (const float*)d_in[12];
  const float* rv2 = (const float*)d_in[13];

  constexpr int N = 16384, F = 512, H = 512, C = 128;
  float* x1 = (float*)d_out;                      // [N][C]
  float* x2 = (float*)d_out + (size_t)N * C;      // [N][H]

  char* wsp = (char*)d_ws;
  u16* xb  = (u16*)wsp;  wsp += (size_t)N * F * 2;   // bn1(x) bf16
  u16* t_t = (u16*)wsp;  wsp += (size_t)H * N * 2;   // (bn1x@w1)^T
  u16* z_t = (u16*)wsp;  wsp += (size_t)C * N * 2;   // (x2@w2)^T
  u16* w1t = (u16*)wsp;  wsp += (size_t)H * F * 2;   // w1^T
  u16* w2t = (u16*)wsp;  wsp += (size_t)C * H * 2;   // w2^T
  float* Pp = (float*)wsp;                           // partials (P2: 2x32MB)

  bn1_cast_k<<<(N * F / 8) / 256, 256, 0, stream>>>(x, g1, be1, rm1, rv1, xb);
  tcvt_k<<<(F * H) / 256, 256, 0, stream>>>(w1, w1t, H);
  tcvt_k<<<(H * C) / 256, 256, 0, stream>>>(w2, w2t, C);

  // P1: t = xb @ w1t -> t_t[h][n]   (N-split 2, grid 512, 2/CU)
  gk<64, 512, 256, 64, false, 0, 0, 2, 1, 1><<<512, 512, 0, stream>>>(
      xb, w1t, F, N, nullptr, t_t);

  // P2: a @ t partials (BM=128, N-split 2 x K-split 2, XCD-combo map,
  //     per-XCD B slice = 4MB = L2-resident; grid 512, 2/CU)
  gk<128, 512, 256, 32, true, 2, 1, 2, 2, 2><<<512, 512, 0, stream>>>(
      a, t_t, N, N, Pp, nullptr);

  // C2: x2 = bn2(relu(P0 + P1 + b1))
  comb_bn_k<<<(N * H / 4) / 256, 256, 0, stream>>>(Pp, b1, g2, be2, rm2, rv2,
                                                   x2);

  // P3: z = x2 @ w2t -> z_t[c][n]   (grid 256)
  gk<64, 128, 128, 64, true, 0, 0, 1, 1, 2><<<256, 512, 0, stream>>>(
      x2, w2t, H, N, nullptr, z_t);

  // P4: a @ z partials (K-split 2, grid 512, 2/CU) -> Pp
  gk<64, 128, 128, 64, true, 2, 0, 1, 2, 2><<<512, 512, 0, stream>>>(
      a, z_t, N, N, Pp, nullptr);

  // C4: x1 = P0 + P1 + b2
  comb_k<<<(N * C / 4) / 256, 256, 0, stream>>>(Pp, b2, x1);
}

// Round 11
// 982.546 us; speedup vs baseline: 1.4123x; 1.4123x over previous
//
#include <hip/hip_runtime.h>
#include <hip/hip_bf16.h>

typedef unsigned short u16;
typedef unsigned int u32;
typedef __attribute__((ext_vector_type(4))) float f32x4;
typedef __attribute__((ext_vector_type(8))) short bf16x8;

#define DEVI static __device__ __forceinline__

DEVI u16 f2bf(float f) {
  u32 u = __builtin_bit_cast(u32, f);
  u += 0x7fffu + ((u >> 16) & 1u);
  return (u16)(u >> 16);
}

DEVI void gload_lds16(const void* g, void* l) {
  __builtin_amdgcn_global_load_lds(
      (const __attribute__((address_space(1))) u32*)g,
      (__attribute__((address_space(3))) u32*)l, 16, 0, 0);
}

template<int N> DEVI void wait_vm() {
  if constexpr (N == 0)      asm volatile("s_waitcnt vmcnt(0)" ::: "memory");
  else if constexpr (N == 5) asm volatile("s_waitcnt vmcnt(5)" ::: "memory");
  else if constexpr (N == 6) asm volatile("s_waitcnt vmcnt(6)" ::: "memory");
  else if constexpr (N == 8) asm volatile("s_waitcnt vmcnt(8)" ::: "memory");
  else                       asm volatile("s_waitcnt vmcnt(0)" ::: "memory");
}
DEVI void lgkm_barrier() {
  asm volatile("s_waitcnt lgkmcnt(0)\n\ts_barrier" ::: "memory");
}

struct Aregs { f32x4 v0, v1; uint4 h; };

// ---------------------------------------------------------------------------
// C[BM x BN_T] = A[m0.., k0..k0+klen] @ Bt[n0.., k]^T (bf16 Bt).
// 512 thr = 8 waves (1x8 over BN_T cols). A: reg-staged (fp32->bf16 or bf16),
// 2 named reg sets, XOR-swizzled ds_write into LDS dbuf. B: per-wave slice
// via global_load_lds (inverse-swizzled source), DEPTH<=2, NB=DEPTH+1 bufs.
// Counted waits: VMW = DEPTH*(LA+LB); one lgkmcnt(0)+s_barrier per step;
// vmcnt(0) drain before epilogue. NT even at all call sites.
// CHUNK = BM*BK/512 elems/thread: 8 (16B A chunk) or 4 (8B, BM=64/BK=32).
// XMAP 0: q=(bid&7)*G8+(bid>>3); sub=q%SPL (nh or kc); m0=(q/SPL)*BM.
// XMAP 2: (new P2) kc = xcd>>1 (4 chunks, XCD-pair each; per-XCD B = 4MB
//         = L2-resident); m0 = ((bid>>3) + (xcd&1)*128)*BM; grid 1024.
// EPI 0: bf16 transposed outh[n][M]+m.  EPI 2: fp32 partial outf+kc*M*BN_FULL.
// MINB = 2nd launch_bounds arg. MEASURED TOOLCHAIN SEMANTICS (r8/r10 spills):
//   arg is min BLOCKS/CU: (512,2) -> 128 VGPR cap; (512,4) -> 64 VGPR cap.
//   acc<=32 VGPR kernels use MINB=4; acc=64 kernels MUST use MINB=2.
// ---------------------------------------------------------------------------
template<int BM, int BN_FULL, int BN_T, int BK, bool AF32, int EPI, int XMAP,
         int NSPL, int KSPL, int DEPTH, int MINB>
__global__ __launch_bounds__(512, MINB)
void gk(const void* __restrict__ Ap, const u16* __restrict__ Bt,
        const int Kfull, const int M, float* __restrict__ outf,
        u16* __restrict__ outh)
{
  constexpr int TN = BN_T / 8;
  constexpr int MF = BM / 16, NF = TN / 16, KK = BK / 32;
  constexpr int ABYTES = BM * BK * 2;
  constexpr int SLICE = TN * BK * 2;
  constexpr int LB = SLICE / 1024;
  constexpr int CHUNK = BM * BK / 512;     // 8 or 4 elems per thread
  constexpr int LA = (AF32 && CHUNK == 8) ? 2 : 1;
  constexpr int NB = DEPTH + 1;
  constexpr int VMW = DEPTH * (LA + LB);
  constexpr int CPR = BK / CHUNK;          // A chunks per row
  constexpr int SPL = NSPL * KSPL;
  static_assert(CHUNK == 8 || CHUNK == 4, "chunk");
  static_assert(DEPTH <= 2, "DEPTH=3 wait algebra unsound (r9 post-mortem)");

  __shared__ char smem[2 * ABYTES + NB * 8 * SLICE];

  const int tid = threadIdx.x;
  const int w = tid >> 6, l = tid & 63;
  const int l15 = l & 15, l4 = l >> 4;

  int m0, nh, kc;
  if constexpr (XMAP == 2) {
    const int xcd = blockIdx.x & 7;
    kc = xcd >> 1;                         // 4 k-chunks, one per XCD pair
    nh = 0;
    m0 = ((int)(blockIdx.x >> 3) + (xcd & 1) * 128) * BM;
  } else {
    const int G8 = gridDim.x >> 3;
    const int q = (blockIdx.x & 7) * G8 + (blockIdx.x >> 3);
    const int sub = q % SPL;
    m0 = (q / SPL) * BM;
    nh = (NSPL == 2) ? sub : 0;
    kc = (KSPL == 2) ? sub : 0;
  }
  const int n0 = nh * BN_T;
  const int klen = Kfull / KSPL;
  const int k0 = kc * klen;
  const int NT = klen / BK;

  auto off = [&](int row, int chq) -> int {
    if constexpr (BK == 64) return row * 128 + ((chq ^ (row & 7)) << 4);
    else                    return row * 64 + ((chq ^ ((row >> 1) & 3)) << 4);
  };

  const int ar = tid / CPR, ac = tid % CPR;
  int apos;
  if constexpr (CHUNK == 4)
    apos = ar * 64 + ((((ac >> 1) ^ ((ar >> 1) & 3))) << 4) + (ac & 1) * 8;
  else
    apos = off(ar, ac);
  const size_t Abase = (size_t)(m0 + ar) * Kfull + k0 + (size_t)ac * CHUNK;

  char* const bslice = smem + 2 * ABYTES + w * SLICE;

  f32x4 acc[MF][NF];
#pragma unroll
  for (int i = 0; i < MF; ++i)
#pragma unroll
    for (int j = 0; j < NF; ++j) acc[i][j] = (f32x4){0.f, 0.f, 0.f, 0.f};

  Aregs R0, R1;

  auto issueA = [&](Aregs& R, int t) {
    if constexpr (AF32 && CHUNK == 8) {
      const float* p = (const float*)Ap + Abase + (size_t)t * BK;
      R.v0 = *(const f32x4*)p;
      R.v1 = *(const f32x4*)(p + 4);
    } else if constexpr (AF32) {
      const float* p = (const float*)Ap + Abase + (size_t)t * BK;
      R.v0 = *(const f32x4*)p;
    } else {
      const u16* p = (const u16*)Ap + Abase + (size_t)t * BK;
      R.h = *(const uint4*)p;
    }
  };
  auto writeA = [&](int nb, Aregs& R) {
    if constexpr (CHUNK == 4) {
      uint2 pk;
      pk.x = (u32)f2bf(R.v0[0]) | ((u32)f2bf(R.v0[1]) << 16);
      pk.y = (u32)f2bf(R.v0[2]) | ((u32)f2bf(R.v0[3]) << 16);
      *(uint2*)(smem + nb * ABYTES + apos) = pk;
    } else {
      uint4 pk;
      if constexpr (AF32) {
        pk.x = (u32)f2bf(R.v0[0]) | ((u32)f2bf(R.v0[1]) << 16);
        pk.y = (u32)f2bf(R.v0[2]) | ((u32)f2bf(R.v0[3]) << 16);
        pk.z = (u32)f2bf(R.v1[0]) | ((u32)f2bf(R.v1[1]) << 16);
        pk.w = (u32)f2bf(R.v1[2]) | ((u32)f2bf(R.v1[3]) << 16);
      } else {
        pk = R.h;
      }
      *(uint4*)(smem + nb * ABYTES + apos) = pk;
    }
  };
  auto issueB = [&](int nb, int t) {
    const char* bsrc = (const char*)Bt +
                       ((size_t)(n0 + w * TN) * Kfull + k0 +
                        (size_t)t * BK) * 2;
    char* bd = bslice + nb * (8 * SLICE);
#pragma unroll
    for (int i = 0; i < LB; ++i) {
      const int p = i * 1024 + l * 16;
      const int nl = (BK == 64) ? (p >> 7) : (p >> 6);
      const int chp = (p & (BK * 2 - 1)) >> 4;
      const int chq = (BK == 64) ? (chp ^ (nl & 7)) : (chp ^ ((nl >> 1) & 3));
      gload_lds16(bsrc + (size_t)nl * ((size_t)Kfull * 2) + chq * 16,
                  bd + i * 1024);
    }
  };
  auto compute = [&](int ab, int bb) {
    const char* A = smem + ab * ABYTES;
    const char* Bs = bslice + bb * (8 * SLICE);
#pragma unroll
    for (int kk = 0; kk < KK; ++kk) {
      bf16x8 af[MF];
      uint4 bfr[NF];
#pragma unroll
      for (int mi = 0; mi < MF; ++mi)
        af[mi] = *(const bf16x8*)(A + off(mi * 16 + l15, kk * 4 + l4));
#pragma unroll
      for (int ni = 0; ni < NF; ++ni)
        bfr[ni] = *(const uint4*)(Bs + off(ni * 16 + l15, kk * 4 + l4));
      __builtin_amdgcn_s_setprio(1);
#pragma unroll
      for (int mi = 0; mi < MF; ++mi)
#pragma unroll
        for (int ni = 0; ni < NF; ++ni)
          acc[mi][ni] = __builtin_amdgcn_mfma_f32_16x16x32_bf16(
              af[mi], __builtin_bit_cast(bf16x8, bfr[ni]), acc[mi][ni],
              0, 0, 0);
      __builtin_amdgcn_s_setprio(0);
    }
  };

  // prologue
  issueB(0, 0);
  issueA(R0, 0);
  issueA(R1, NT > 1 ? 1 : 0);
  if constexpr (DEPTH == 2) issueB(1, NT > 1 ? 1 : 0);
  writeA(0, R0);
  lgkm_barrier();

  int bc = 0, bi = DEPTH % NB;
  int t2 = 0;

#define SUBSTEP(RI, RW, ABUF)                                                \
  {                                                                          \
    const int tA = (t2 + 2 < NT) ? t2 + 2 : NT - 1;                          \
    const int tB = (t2 + DEPTH < NT) ? t2 + DEPTH : NT - 1;                  \
    issueA(RI, tA);                                                          \
    issueB(bi, tB);                                                          \
    wait_vm<VMW>();                                                          \
    compute(ABUF, bc);                                                       \
    writeA(ABUF ^ 1, RW);                                                    \
    lgkm_barrier();                                                          \
    bc = (bc + 1 == NB) ? 0 : bc + 1;                                        \
    bi = (bi + 1 == NB) ? 0 : bi + 1;                                        \
    ++t2;                                                                    \
  }

  for (int it = 0; it < NT / 2; ++it) {
    SUBSTEP(R0, R1, 0);
    SUBSTEP(R1, R0, 1);
  }
#undef SUBSTEP

  wait_vm<0>();   // drain clamped-tail gload_lds

  const int mrow0 = m0 + l4 * 4;
#pragma unroll
  for (int ni = 0; ni < NF; ++ni) {
    const int n = n0 + w * TN + ni * 16 + l15;
    if constexpr (EPI == 0) {
#pragma unroll
      for (int mi = 0; mi < MF; ++mi) {
        const int m = mrow0 + mi * 16;
        ushort4 o;
        o.x = f2bf(acc[mi][ni][0]);
        o.y = f2bf(acc[mi][ni][1]);
        o.z = f2bf(acc[mi][ni][2]);
        o.w = f2bf(acc[mi][ni][3]);
        *(ushort4*)(outh + (size_t)n * M + m) = o;
      }
    } else {
      float* Pout = outf + (size_t)kc * ((size_t)M * BN_FULL);
#pragma unroll
      for (int mi = 0; mi < MF; ++mi)
#pragma unroll
        for (int r = 0; r < 4; ++r)
          Pout[(size_t)(mrow0 + mi * 16 + r) * BN_FULL + n] = acc[mi][ni][r];
    }
  }
}

// ---------------------------------------------------------------------------
__global__ __launch_bounds__(256)
void bn1_cast_k(const float* __restrict__ x, const float* __restrict__ g,
                const float* __restrict__ be, const float* __restrict__ rm,
                const float* __restrict__ rv, u16* __restrict__ out)
{
  const size_t i8 = ((size_t)blockIdx.x * 256 + threadIdx.x) * 8;
  const f32x4 v0 = *(const f32x4*)(x + i8);
  const f32x4 v1 = *(const f32x4*)(x + i8 + 4);
  const int f0 = (int)(i8 & 511);
  u16 u[8];
#pragma unroll
  for (int e = 0; e < 8; ++e) {
    const int f = f0 + e;
    const float sc = g[f] * rsqrtf(rv[f] + 1e-5f);
    const float v = (e < 4) ? v0[e] : v1[e - 4];
    u[e] = f2bf((v - rm[f]) * sc + be[f]);
  }
  uint4 o;
  o.x = (u32)u[0] | ((u32)u[1] << 16);
  o.y = (u32)u[2] | ((u32)u[3] << 16);
  o.z = (u32)u[4] | ((u32)u[5] << 16);
  o.w = (u32)u[6] | ((u32)u[7] << 16);
  *(uint4*)(out + i8) = o;
}

__global__ __launch_bounds__(256)
void tcvt_k(const float* __restrict__ in, u16* __restrict__ out, int rowlen)
{
  const int o = blockIdx.x * 256 + threadIdx.x;
  out[o] = f2bf(in[(size_t)(o & 511) * rowlen + (o >> 9)]);
}

// x2 = bn2(relu(P0+P1+P2+P3 + b1)); row length 512
__global__ __launch_bounds__(256)
void comb_bn_k(const float* __restrict__ P, const float* __restrict__ b1,
               const float* __restrict__ g2, const float* __restrict__ be2,
               const float* __restrict__ rm2, const float* __restrict__ rv2,
               float* __restrict__ out)
{
  const size_t i4 = ((size_t)blockIdx.x * 256 + threadIdx.x) * 4;
  f32x4 s = *(const f32x4*)(P + i4);
#pragma unroll
  for (int c = 1; c < 4; ++c) {
    const f32x4 p = *(const f32x4*)(P + (size_t)c * (16384ull * 512) + i4);
#pragma unroll
    for (int e = 0; e < 4; ++e) s[e] += p[e];
  }
  const int f0 = (int)(i4 & 511);
  f32x4 o;
#pragma unroll
  for (int e = 0; e < 4; ++e) {
    const int f = f0 + e;
    const float v = fmaxf(s[e] + b1[f], 0.f);
    const float sc = g2[f] * rsqrtf(rv2[f] + 1e-5f);
    o[e] = v * sc + (be2[f] - rm2[f] * sc);
  }
  *(f32x4*)(out + i4) = o;
}

// x1 = P0 + P1 + b2; row length 128
__global__ __launch_bounds__(256)
void comb_k(const float* __restrict__ P, const float* __restrict__ b2,
            float* __restrict__ out)
{
  const size_t i4 = ((size_t)blockIdx.x * 256 + threadIdx.x) * 4;
  const f32x4 p0 = *(const f32x4*)(P + i4);
  const f32x4 p1 = *(const f32x4*)(P + (size_t)16384 * 128 + i4);
  const int f0 = (int)(i4 & 127);
  f32x4 o;
#pragma unroll
  for (int e = 0; e < 4; ++e) o[e] = p0[e] + p1[e] + b2[f0 + e];
  *(f32x4*)(out + i4) = o;
}

// ---------------------------------------------------------------------------
extern "C" void kernel_launch(void* const* d_in, const int* in_sizes, int n_in,
                              void* d_out, int out_size, void* d_ws, size_t ws_size,
                              hipStream_t stream)
{
  const float* x   = (const float*)d_in[0];
  const float* a   = (const float*)d_in[1];
  const float* w1  = (const float*)d_in[2];
  const float* b1  = (const float*)d_in[3];
  const float* w2  = (const float*)d_in[4];
  const float* b2  = (const float*)d_in[5];
  const float* g1  = (const float*)d_in[6];
  const float* be1 = (const float*)d_in[7];
  const float* rm1 = (const float*)d_in[8];
  const float* rv1 = (const float*)d_in[9];
  const float* g2  = (const float*)d_in[10];
  const float* be2 = (const float*)d_in[11];
  const float* rm2 = (const float*)d_in[12];
  const float* rv2 = (const float*)d_in[13];

  constexpr int N = 16384, F = 512, H = 512, C = 128;
  float* x1 = (float*)d_out;                      // [N][C]
  float* x2 = (float*)d_out + (size_t)N * C;      // [N][H]

  char* wsp = (char*)d_ws;
  u16* xb  = (u16*)wsp;  wsp += (size_t)N * F * 2;   // bn1(x) bf16
  u16* t_t = (u16*)wsp;  wsp += (size_t)H * N * 2;   // (bn1x@w1)^T
  u16* z_t = (u16*)wsp;  wsp += (size_t)C * N * 2;   // (x2@w2)^T
  u16* w1t = (u16*)wsp;  wsp += (size_t)H * F * 2;   // w1^T
  u16* w2t = (u16*)wsp;  wsp += (size_t)C * H * 2;   // w2^T
  float* Pp = (float*)wsp;                           // partials (P2: 4x32MB)

  bn1_cast_k<<<(N * F / 8) / 256, 256, 0, stream>>>(x, g1, be1, rm1, rv1, xb);
  tcvt_k<<<(F * H) / 256, 256, 0, stream>>>(w1, w1t, H);
  tcvt_k<<<(H * C) / 256, 256, 0, stream>>>(w2, w2t, C);

  // P1: t = xb @ w1t -> t_t[h][n]   (N-split 2, grid 512, 2/CU) — as r9
  gk<64, 512, 256, 64, false, 0, 0, 2, 1, 1, 4><<<512, 512, 0, stream>>>(
      xb, w1t, F, N, nullptr, t_t);

  // P2: a @ t partials (BM=64/BK=32, full BN=512, K-split 4 per XCD-pair,
  //     B L2-resident, A read ONCE; grid 1024, 2/CU, MINB=2 -> 128 VGPR cap)
  gk<64, 512, 512, 32, true, 2, 2, 1, 4, 1, 2><<<1024, 512, 0, stream>>>(
      a, t_t, N, N, Pp, nullptr);

  // C2: x2 = bn2(relu(P0+P1+P2+P3 + b1))
  comb_bn_k<<<(N * H / 4) / 256, 256, 0, stream>>>(Pp, b1, g2, be2, rm2, rv2,
                                                   x2);

  // P3: z = x2 @ w2t -> z_t[c][n]   (grid 256) — as r9
  gk<64, 128, 128, 64, true, 0, 0, 1, 1, 2, 4><<<256, 512, 0, stream>>>(
      x2, w2t, H, N, nullptr, z_t);

  // P4: a @ z partials (K-split 2, grid 512, 2/CU) -> Pp — as r9
  gk<64, 128, 128, 64, true, 2, 0, 1, 2, 2, 4><<<512, 512, 0, stream>>>(
      a, z_t, N, N, Pp, nullptr);

  // C4: x1 = P0 + P1 + b2
  comb_k<<<(N * C / 4) / 256, 256, 0, stream>>>(Pp, b2, x1);
}

// Round 12
// 719.753 us; speedup vs baseline: 1.9280x; 1.3651x over previous
//
#include <hip/hip_runtime.h>
#include <hip/hip_bf16.h>

typedef unsigned short u16;
typedef unsigned int u32;
typedef __attribute__((ext_vector_type(4))) float f32x4;
typedef __attribute__((ext_vector_type(8))) short bf16x8;

#define DEVI static __device__ __forceinline__

DEVI u16 f2bf(float f) {
  u32 u = __builtin_bit_cast(u32, f);
  u += 0x7fffu + ((u >> 16) & 1u);
  return (u16)(u >> 16);
}

DEVI void gload_lds16(const void* g, void* l) {
  __builtin_amdgcn_global_load_lds(
      (const __attribute__((address_space(1))) u32*)g,
      (__attribute__((address_space(3))) u32*)l, 16, 0, 0);
}

template<int N> DEVI void wait_vm() {
  if constexpr (N == 0)      asm volatile("s_waitcnt vmcnt(0)" ::: "memory");
  else if constexpr (N == 5) asm volatile("s_waitcnt vmcnt(5)" ::: "memory");
  else if constexpr (N == 6) asm volatile("s_waitcnt vmcnt(6)" ::: "memory");
  else if constexpr (N == 8) asm volatile("s_waitcnt vmcnt(8)" ::: "memory");
  else                       asm volatile("s_waitcnt vmcnt(0)" ::: "memory");
}
DEVI void lgkm_barrier() {
  asm volatile("s_waitcnt lgkmcnt(0)\n\ts_barrier" ::: "memory");
}

struct Aregs { f32x4 v0, v1; uint4 h; };

// ---------------------------------------------------------------------------
// C[64 x BN_T] = A[m0.., k0..k0+klen] @ Bt[n0.., k]^T (bf16 Bt).
// 512 thr = 8 waves (1x8 over BN_T cols). BM=64, BK=64 (the proven config).
// A: reg-staged (fp32->bf16 or bf16), 2 named reg sets, XOR-swizzled ds_write
// into 16KB LDS dbuf. B: per-wave slice via global_load_lds (inverse-swizzled
// source), DEPTH<=2, NB=DEPTH+1 bufs. Counted waits: VMW = DEPTH*(LA+LB);
// one lgkmcnt(0)+s_barrier per step; vmcnt(0) drain before epilogue.
// XMAP 0: q=(bid&7)*G8+(bid>>3); sub=q%SPL (nh or kc); m0=(q/SPL)*BM.
// XMAP 3: (P2) nh = xcd&1 -> XCD-UNIFORM B-half; the XCD's 64 blocks sweep
//   the same 8MB B-half in near-lockstep -> streaming k-window stays
//   L2-resident -> B re-reads become L2 hits instead of 4GB of L3 traffic.
//   m0 = ((bid>>3) + 64*(xcd>>1))*BM (contiguous A slab per XCD). grid 512.
// EPI 0: bf16 transposed outh[n][M]+m.
// EPI 1: outf[m][BN_FULL] = bn2(relu(acc+e0)) fused (e1..e4 = g2,be2,rm2,rv2)
// EPI 2: fp32 partial -> outf + kc*M*BN_FULL.
// MINB semantics (MEASURED, r9/r10 spills): 2nd arg = min BLOCKS/CU:
//   (512,2) -> 128 VGPR cap; (512,4) -> 64 VGPR cap. acc<=32 -> MINB=4 ok.
// ---------------------------------------------------------------------------
template<int BM, int BN_FULL, int BN_T, int BK, bool AF32, int EPI, int XMAP,
         int NSPL, int KSPL, int DEPTH, int MINB>
__global__ __launch_bounds__(512, MINB)
void gk(const void* __restrict__ Ap, const u16* __restrict__ Bt,
        const int Kfull, const int M, float* __restrict__ outf,
        u16* __restrict__ outh,
        const float* __restrict__ e0, const float* __restrict__ e1,
        const float* __restrict__ e2, const float* __restrict__ e3,
        const float* __restrict__ e4)
{
  constexpr int TN = BN_T / 8;
  constexpr int MF = BM / 16, NF = TN / 16, KK = BK / 32;
  constexpr int ABYTES = BM * BK * 2;
  constexpr int SLICE = TN * BK * 2;
  constexpr int LB = SLICE / 1024;
  constexpr int LA = AF32 ? 2 : 1;
  constexpr int NB = DEPTH + 1;
  constexpr int VMW = DEPTH * (LA + LB);
  constexpr int CPR = BK / 8;
  constexpr int SPL = NSPL * KSPL;
  static_assert(BM * BK == 4096, "one 16B A chunk per thread");
  static_assert(DEPTH <= 2, "DEPTH=3 wait algebra unsound");

  __shared__ char smem[2 * ABYTES + NB * 8 * SLICE];

  const int tid = threadIdx.x;
  const int w = tid >> 6, l = tid & 63;
  const int l15 = l & 15, l4 = l >> 4;

  int m0, nh, kc;
  if constexpr (XMAP == 3) {
    const int xcd = blockIdx.x & 7;
    nh = xcd & 1;                          // B-half uniform per XCD
    kc = 0;
    m0 = ((int)(blockIdx.x >> 3) + 64 * (xcd >> 1)) * BM;
  } else {
    const int G8 = gridDim.x >> 3;
    const int q = (blockIdx.x & 7) * G8 + (blockIdx.x >> 3);
    const int sub = q % SPL;
    m0 = (q / SPL) * BM;
    nh = (NSPL == 2) ? sub : 0;
    kc = (KSPL == 2) ? sub : 0;
  }
  const int n0 = nh * BN_T;
  const int klen = Kfull / KSPL;
  const int k0 = kc * klen;
  const int NT = klen / BK;

  auto off = [&](int row, int chq) -> int {
    return row * 128 + ((chq ^ (row & 7)) << 4);
  };

  const int ar = tid / CPR, ac = tid % CPR;
  const int apos = off(ar, ac);
  const size_t Abase = (size_t)(m0 + ar) * Kfull + k0 + (size_t)ac * 8;

  char* const bslice = smem + 2 * ABYTES + w * SLICE;

  f32x4 acc[MF][NF];
#pragma unroll
  for (int i = 0; i < MF; ++i)
#pragma unroll
    for (int j = 0; j < NF; ++j) acc[i][j] = (f32x4){0.f, 0.f, 0.f, 0.f};

  Aregs R0, R1;

  auto issueA = [&](Aregs& R, int t) {
    if constexpr (AF32) {
      const float* p = (const float*)Ap + Abase + (size_t)t * BK;
      R.v0 = *(const f32x4*)p;
      R.v1 = *(const f32x4*)(p + 4);
    } else {
      const u16* p = (const u16*)Ap + Abase + (size_t)t * BK;
      R.h = *(const uint4*)p;
    }
  };
  auto writeA = [&](int nb, Aregs& R) {
    uint4 pk;
    if constexpr (AF32) {
      pk.x = (u32)f2bf(R.v0[0]) | ((u32)f2bf(R.v0[1]) << 16);
      pk.y = (u32)f2bf(R.v0[2]) | ((u32)f2bf(R.v0[3]) << 16);
      pk.z = (u32)f2bf(R.v1[0]) | ((u32)f2bf(R.v1[1]) << 16);
      pk.w = (u32)f2bf(R.v1[2]) | ((u32)f2bf(R.v1[3]) << 16);
    } else {
      pk = R.h;
    }
    *(uint4*)(smem + nb * ABYTES + apos) = pk;
  };
  auto issueB = [&](int nb, int t) {
    const char* bsrc = (const char*)Bt +
                       ((size_t)(n0 + w * TN) * Kfull + k0 +
                        (size_t)t * BK) * 2;
    char* bd = bslice + nb * (8 * SLICE);
#pragma unroll
    for (int i = 0; i < LB; ++i) {
      const int p = i * 1024 + l * 16;
      const int nl = p >> 7;
      const int chq = ((p & 127) >> 4) ^ (nl & 7);
      gload_lds16(bsrc + (size_t)nl * ((size_t)Kfull * 2) + chq * 16,
                  bd + i * 1024);
    }
  };
  auto compute = [&](int ab, int bb) {
    const char* A = smem + ab * ABYTES;
    const char* Bs = bslice + bb * (8 * SLICE);
#pragma unroll
    for (int kk = 0; kk < KK; ++kk) {
      bf16x8 af[MF];
      uint4 bfr[NF];
#pragma unroll
      for (int mi = 0; mi < MF; ++mi)
        af[mi] = *(const bf16x8*)(A + off(mi * 16 + l15, kk * 4 + l4));
#pragma unroll
      for (int ni = 0; ni < NF; ++ni)
        bfr[ni] = *(const uint4*)(Bs + off(ni * 16 + l15, kk * 4 + l4));
      __builtin_amdgcn_s_setprio(1);
#pragma unroll
      for (int mi = 0; mi < MF; ++mi)
#pragma unroll
        for (int ni = 0; ni < NF; ++ni)
          acc[mi][ni] = __builtin_amdgcn_mfma_f32_16x16x32_bf16(
              af[mi], __builtin_bit_cast(bf16x8, bfr[ni]), acc[mi][ni],
              0, 0, 0);
      __builtin_amdgcn_s_setprio(0);
    }
  };

  // prologue
  issueB(0, 0);
  issueA(R0, 0);
  issueA(R1, NT > 1 ? 1 : 0);
  if constexpr (DEPTH == 2) issueB(1, NT > 1 ? 1 : 0);
  writeA(0, R0);
  lgkm_barrier();

  int bc = 0, bi = DEPTH % NB;
  int t2 = 0;

#define SUBSTEP(RI, RW, ABUF)                                                \
  {                                                                          \
    const int tA = (t2 + 2 < NT) ? t2 + 2 : NT - 1;                          \
    const int tB = (t2 + DEPTH < NT) ? t2 + DEPTH : NT - 1;                  \
    issueA(RI, tA);                                                          \
    issueB(bi, tB);                                                          \
    wait_vm<VMW>();                                                          \
    compute(ABUF, bc);                                                       \
    writeA(ABUF ^ 1, RW);                                                    \
    lgkm_barrier();                                                          \
    bc = (bc + 1 == NB) ? 0 : bc + 1;                                        \
    bi = (bi + 1 == NB) ? 0 : bi + 1;                                        \
    ++t2;                                                                    \
  }

  for (int it = 0; it < NT / 2; ++it) {
    SUBSTEP(R0, R1, 0);
    SUBSTEP(R1, R0, 1);
  }
#undef SUBSTEP

  wait_vm<0>();   // drain clamped-tail gload_lds

  const int mrow0 = m0 + l4 * 4;
#pragma unroll
  for (int ni = 0; ni < NF; ++ni) {
    const int n = n0 + w * TN + ni * 16 + l15;
    if constexpr (EPI == 0) {
#pragma unroll
      for (int mi = 0; mi < MF; ++mi) {
        const int m = mrow0 + mi * 16;
        ushort4 o;
        o.x = f2bf(acc[mi][ni][0]);
        o.y = f2bf(acc[mi][ni][1]);
        o.z = f2bf(acc[mi][ni][2]);
        o.w = f2bf(acc[mi][ni][3]);
        *(ushort4*)(outh + (size_t)n * M + m) = o;
      }
    } else if constexpr (EPI == 1) {
      const float b1v = e0[n];
      const float sc = e1[n] * rsqrtf(e4[n] + 1e-5f);
      const float sh = e2[n] - e3[n] * sc;
#pragma unroll
      for (int mi = 0; mi < MF; ++mi)
#pragma unroll
        for (int r = 0; r < 4; ++r) {
          const float s = fmaxf(acc[mi][ni][r] + b1v, 0.f);
          outf[(size_t)(mrow0 + mi * 16 + r) * BN_FULL + n] = s * sc + sh;
        }
    } else {
      float* Pout = outf + (size_t)kc * ((size_t)M * BN_FULL);
#pragma unroll
      for (int mi = 0; mi < MF; ++mi)
#pragma unroll
        for (int r = 0; r < 4; ++r)
          Pout[(size_t)(mrow0 + mi * 16 + r) * BN_FULL + n] = acc[mi][ni][r];
    }
  }
}

// ---------------------------------------------------------------------------
__global__ __launch_bounds__(256)
void bn1_cast_k(const float* __restrict__ x, const float* __restrict__ g,
                const float* __restrict__ be, const float* __restrict__ rm,
                const float* __restrict__ rv, u16* __restrict__ out)
{
  const size_t i8 = ((size_t)blockIdx.x * 256 + threadIdx.x) * 8;
  const f32x4 v0 = *(const f32x4*)(x + i8);
  const f32x4 v1 = *(const f32x4*)(x + i8 + 4);
  const int f0 = (int)(i8 & 511);
  u16 u[8];
#pragma unroll
  for (int e = 0; e < 8; ++e) {
    const int f = f0 + e;
    const float sc = g[f] * rsqrtf(rv[f] + 1e-5f);
    const float v = (e < 4) ? v0[e] : v1[e - 4];
    u[e] = f2bf((v - rm[f]) * sc + be[f]);
  }
  uint4 o;
  o.x = (u32)u[0] | ((u32)u[1] << 16);
  o.y = (u32)u[2] | ((u32)u[3] << 16);
  o.z = (u32)u[4] | ((u32)u[5] << 16);
  o.w = (u32)u[6] | ((u32)u[7] << 16);
  *(uint4*)(out + i8) = o;
}

__global__ __launch_bounds__(256)
void tcvt_k(const float* __restrict__ in, u16* __restrict__ out, int rowlen)
{
  const int o = blockIdx.x * 256 + threadIdx.x;
  out[o] = f2bf(in[(size_t)(o & 511) * rowlen + (o >> 9)]);
}

// x1 = P0 + P1 + b2; row length 128
__global__ __launch_bounds__(256)
void comb_k(const float* __restrict__ P, const float* __restrict__ b2,
            float* __restrict__ out)
{
  const size_t i4 = ((size_t)blockIdx.x * 256 + threadIdx.x) * 4;
  const f32x4 p0 = *(const f32x4*)(P + i4);
  const f32x4 p1 = *(const f32x4*)(P + (size_t)16384 * 128 + i4);
  const int f0 = (int)(i4 & 127);
  f32x4 o;
#pragma unroll
  for (int e = 0; e < 4; ++e) o[e] = p0[e] + p1[e] + b2[f0 + e];
  *(f32x4*)(out + i4) = o;
}

// ---------------------------------------------------------------------------
extern "C" void kernel_launch(void* const* d_in, const int* in_sizes, int n_in,
                              void* d_out, int out_size, void* d_ws, size_t ws_size,
                              hipStream_t stream)
{
  const float* x   = (const float*)d_in[0];
  const float* a   = (const float*)d_in[1];
  const float* w1  = (const float*)d_in[2];
  const float* b1  = (const float*)d_in[3];
  const float* w2  = (const float*)d_in[4];
  const float* b2  = (const float*)d_in[5];
  const float* g1  = (const float*)d_in[6];
  const float* be1 = (const float*)d_in[7];
  const float* rm1 = (const float*)d_in[8];
  const float* rv1 = (const float*)d_in[9];
  const float* g2  = (const float*)d_in[10];
  const float* be2 = (const float*)d_in[11];
  const float* rm2 = (const float*)d_in[12];
  const float* rv2 = (const float*)d_in[13];

  constexpr int N = 16384, F = 512, H = 512, C = 128;
  float* x1 = (float*)d_out;                      // [N][C]
  float* x2 = (float*)d_out + (size_t)N * C;      // [N][H]

  char* wsp = (char*)d_ws;
  u16* xb  = (u16*)wsp;  wsp += (size_t)N * F * 2;   // bn1(x) bf16
  u16* t_t = (u16*)wsp;  wsp += (size_t)H * N * 2;   // (bn1x@w1)^T
  u16* z_t = (u16*)wsp;  wsp += (size_t)C * N * 2;   // (x2@w2)^T
  u16* w1t = (u16*)wsp;  wsp += (size_t)H * F * 2;   // w1^T
  u16* w2t = (u16*)wsp;  wsp += (size_t)C * H * 2;   // w2^T
  float* Pp = (float*)wsp;                           // P4 partials (2x8 MiB)

  bn1_cast_k<<<(N * F / 8) / 256, 256, 0, stream>>>(x, g1, be1, rm1, rv1, xb);
  tcvt_k<<<(F * H) / 256, 256, 0, stream>>>(w1, w1t, H);
  tcvt_k<<<(H * C) / 256, 256, 0, stream>>>(w2, w2t, C);

  // P1: t = xb @ w1t -> t_t[h][n]   (N-split 2, grid 512, 2/CU)
  gk<64, 512, 256, 64, false, 0, 0, 2, 1, 1, 4><<<512, 512, 0, stream>>>(
      xb, w1t, F, N, nullptr, t_t, nullptr, nullptr, nullptr, nullptr, nullptr);

  // P2: x2 = bn2(relu(a @ t + b1)) fused  (N-split 2 XCD-UNIFORM, grid 512)
  gk<64, 512, 256, 64, true, 1, 3, 2, 1, 1, 4><<<512, 512, 0, stream>>>(
      a, t_t, N, N, x2, nullptr, b1, g2, be2, rm2, rv2);

  // P3: z = x2 @ w2t -> z_t[c][n]   (grid 256)
  gk<64, 128, 128, 64, true, 0, 0, 1, 1, 2, 4><<<256, 512, 0, stream>>>(
      x2, w2t, H, N, nullptr, z_t, nullptr, nullptr, nullptr, nullptr, nullptr);

  // P4: a @ z partials (K-split 2, grid 512, 2/CU) -> Pp
  gk<64, 128, 128, 64, true, 2, 0, 1, 2, 2, 4><<<512, 512, 0, stream>>>(
      a, z_t, N, N, Pp, nullptr, nullptr, nullptr, nullptr, nullptr, nullptr);

  // C4: x1 = P0 + P1 + b2
  comb_k<<<(N * C / 4) / 256, 256, 0, stream>>>(Pp, b2, x1);
}